// Round 1
// baseline (365.421 us; speedup 1.0000x reference)
//
#include <hip/hip_runtime.h>
#include <hip/hip_bf16.h>
#include <stdint.h>

#define CH    256
#define HWsz  3136
#define NIMG  32
#define COLS  (NIMG * HWsz)   // 100352
#define KB    32
#define TN    64
#define TILES (COLS / TN)     // 1568
#define PBLK  2               // tiles per block
#define GI_N  (8 * PBLK)      // 16 pipeline iterations per block
#define NBINS 8               // replicated atomic bins (contention spread)

typedef float  f32x4  __attribute__((ext_vector_type(4)));
typedef __bf16 bf16x8 __attribute__((ext_vector_type(8)));

struct Stats {
  float mnsum[NBINS][CH];
  float mn[CH];
  float poff[CH];
  float clF[CH];
  unsigned dminK[NBINS][CH];
  unsigned dmaxK[NBINS][CH];
  float dminF[CH];
  float scaleF[CH];
  float invF[CH];
  float qsum[CH];
  float corr[CH];
  unsigned short u_bf[CH * CH];   // u row-major (A for GEMM2)
  unsigned short uT_bf[CH * CH];  // u transposed (A for GEMM1)
};

__device__ __forceinline__ unsigned short f2bf(float f) {
  union { float f; unsigned u; } v; v.f = f;
  unsigned r = v.u + 0x7fffu + ((v.u >> 16) & 1u);  // RNE
  return (unsigned short)(r >> 16);
}
__device__ __forceinline__ float bf2f(unsigned short b) {
  union { unsigned u; float f; } v; v.u = ((unsigned)b) << 16;
  return v.f;
}
__device__ __forceinline__ unsigned pack_bf2(float a, float b) {
  return (unsigned)f2bf(a) | ((unsigned)f2bf(b) << 16);
}
__device__ __forceinline__ unsigned fkey(float f) {
  unsigned u = __float_as_uint(f);
  return (u & 0x80000000u) ? ~u : (u | 0x80000000u);
}
__device__ __forceinline__ float funkey(unsigned k) {
  unsigned u = (k & 0x80000000u) ? (k & 0x7fffffffu) : ~k;
  return __uint_as_float(u);
}
__device__ __forceinline__ float clampf(float v, float c) {
  return fminf(fmaxf(v, -c), c);
}
__device__ __forceinline__ float dq(float v, float dmin, float sc, float inv) {
  return sc == 0.f ? v : fmaf(rintf((v - dmin) * sc), inv, dmin);
}

// Workgroup barrier WITHOUT the vmcnt(0) drain that __syncthreads() carries.
// LDS writes are made visible via lgkmcnt(0); global loads stay in flight
// across the barrier (compiler keeps its own counted vmcnt for register deps).
__device__ __forceinline__ void wave_barrier() {
  asm volatile("s_waitcnt lgkmcnt(0)" ::: "memory");
  __builtin_amdgcn_s_barrier();
}

// ---- init ---------------------------------------------------------------
__global__ void k_init(const float* __restrict__ u, Stats* st) {
  int b = blockIdx.x, t = threadIdx.x;
  st->u_bf[b * CH + t]  = f2bf(u[b * CH + t]);
  st->uT_bf[b * CH + t] = f2bf(u[t * CH + b]);
  if (b < NBINS) {
    st->mnsum[b][t] = 0.f;
    st->dminK[b][t] = 0xFFFFFFFFu;
    st->dmaxK[b][t] = 0u;
  }
  if (b == 0) st->qsum[t] = 0.f;
}

// ---- GEMM1: p' = uT @ relu(x) raw (bf16 ILV store), fused relu-sums (reg)
// + per-row raw min/max. 2 tiles/block, 3-deep reg pipeline, LDS dbuf.
__global__ __launch_bounds__(256) void k_gemm1(const float* __restrict__ x,
                                               Stats* __restrict__ st,
                                               unsigned* __restrict__ pq,
                                               long nstride) {
  __shared__ __align__(16) unsigned ldsB[2][TN * 20];  // 10240 B
  __shared__ float smin[CH];                           // 1 KB
  __shared__ float smax[CH];                           // 1 KB
  __shared__ float scr[CH][17];                        // 17408 B

  const int t = threadIdx.x;
  const int lane = t & 63, wv = t >> 6;
  const int g = t & 15, cpair = t >> 4;
  const int c2 = cpair & 3;
  const int q = lane >> 4, r15 = lane & 15;
  const int wsw = (((wv ^ ((g >> 1) & 3)) << 2) | c2);  // write swizzle (j>>3 == g>>1)

  const int t0 = blockIdx.x * PBLK;
  const unsigned short* uT = st->uT_bf;

  smin[t] = 1e30f;
  smax[t] = -1e30f;

  f32x4 acc[4][4] = {};
  float4 rA[3], rB[3];
  float relp[8][2] = {};

  auto ld = [&](int gi, int slot) {
    const int tile = t0 + (gi >> 3), kc = gi & 7;
    const int n = tile / 49, hw0 = (tile % 49) * TN;
    const float* p = x + (size_t)n * CH * HWsz + (size_t)(kc * KB + 2 * cpair) * HWsz + hw0 + 4 * g;
    rA[slot] = *(const float4*)p;
    rB[slot] = *(const float4*)(p + HWsz);
  };
  auto stage = [&](int gi, int slot) {
    const int kc = gi & 7, buf = gi & 1;
    const float a[4] = {fmaxf(rA[slot].x, 0.f), fmaxf(rA[slot].y, 0.f),
                        fmaxf(rA[slot].z, 0.f), fmaxf(rA[slot].w, 0.f)};
    const float b[4] = {fmaxf(rB[slot].x, 0.f), fmaxf(rB[slot].y, 0.f),
                        fmaxf(rB[slot].z, 0.f), fmaxf(rB[slot].w, 0.f)};
    relp[kc][0] += (a[0] + a[1]) + (a[2] + a[3]);
    relp[kc][1] += (b[0] + b[1]) + (b[2] + b[3]);
#pragma unroll
    for (int i = 0; i < 4; ++i)
      ldsB[buf][(4 * g + i) * 20 + wsw] = pack_bf2(a[i], b[i]);
  };
  auto epi = [&](int tile) {
    const int n = tile / 49, hw0 = (tile % 49) * TN;
#pragma unroll
    for (int mt = 0; mt < 4; ++mt) {
      const int kp0 = 32 * wv + 8 * mt + 2 * q;
      float mn4[4], mx4[4];
#pragma unroll
      for (int nt = 0; nt < 4; ++nt) {
        const unsigned w01 = pack_bf2(acc[mt][nt][0], acc[mt][nt][1]);
        const unsigned w23 = pack_bf2(acc[mt][nt][2], acc[mt][nt][3]);
        const size_t base = (size_t)n * nstride + (size_t)kp0 * HWsz + hw0 + nt * 16 + r15;
        pq[base]        = w01;
        pq[base + HWsz] = w23;
        const float v[4] = {bf2f((unsigned short)(w01 & 0xffffu)), bf2f((unsigned short)(w01 >> 16)),
                            bf2f((unsigned short)(w23 & 0xffffu)), bf2f((unsigned short)(w23 >> 16))};
#pragma unroll
        for (int reg = 0; reg < 4; ++reg) {
          if (nt == 0) { mn4[reg] = v[reg]; mx4[reg] = v[reg]; }
          else { mn4[reg] = fminf(mn4[reg], v[reg]); mx4[reg] = fmaxf(mx4[reg], v[reg]); }
        }
      }
#pragma unroll
      for (int reg = 0; reg < 4; ++reg) {
#pragma unroll
        for (int m = 8; m; m >>= 1) {
          mn4[reg] = fminf(mn4[reg], __shfl_xor(mn4[reg], m));
          mx4[reg] = fmaxf(mx4[reg], __shfl_xor(mx4[reg], m));
        }
        if (r15 == 0) {
          const int row = 64 * wv + 16 * mt + 4 * q + reg;
          smin[row] = fminf(smin[row], mn4[reg]);
          smax[row] = fmaxf(smax[row], mx4[reg]);
        }
      }
    }
  };

  ld(0, 0); ld(1, 1); ld(2, 2);
  stage(0, 0);

#pragma unroll
  for (int gi = 0; gi < GI_N; ++gi) {
    wave_barrier();
    const int kc = gi & 7;
    bf16x8 afr[4];
#pragma unroll
    for (int mt = 0; mt < 4; ++mt)
      afr[mt] = *(const bf16x8*)(uT + (64 * wv + 16 * mt + r15) * CH + kc * KB + q * 8);
    bf16x8 bfr[4];
#pragma unroll
    for (int nt = 0; nt < 4; ++nt) {
      const int j = nt * 16 + r15;
      bfr[nt] = *(const bf16x8*)((const unsigned short*)ldsB[gi & 1] +
                                 (size_t)j * 40 + ((q ^ ((j >> 3) & 3)) << 3));
    }
    if (gi + 3 < GI_N) ld(gi + 3, (gi + 3) % 3);
    if (gi + 1 < GI_N) stage(gi + 1, (gi + 1) % 3);
#pragma unroll
    for (int nt = 0; nt < 4; ++nt)
#pragma unroll
      for (int mt = 0; mt < 4; ++mt)
        acc[mt][nt] = __builtin_amdgcn_mfma_f32_16x16x32_bf16(afr[mt], bfr[nt], acc[mt][nt], 0, 0, 0);
    if ((gi & 7) == 7) {
      epi(t0 + (gi >> 3));
#pragma unroll
      for (int mt = 0; mt < 4; ++mt)
#pragma unroll
        for (int nt = 0; nt < 4; ++nt)
          acc[mt][nt] = (f32x4)(0.f);
    }
  }

  // relu-sum reduction: regs -> LDS transpose -> one atomic per row per block
  __syncthreads();
#pragma unroll
  for (int kc = 0; kc < 8; ++kc) {
    scr[kc * 32 + 2 * cpair + 0][g] = relp[kc][0];
    scr[kc * 32 + 2 * cpair + 1][g] = relp[kc][1];
  }
  __syncthreads();
  float s = 0.f;
#pragma unroll
  for (int i = 0; i < 16; ++i) s += scr[t][i];
  const int bin = blockIdx.x & (NBINS - 1);
  atomicAdd(&st->mnsum[bin][t], s);
  atomicMin(&st->dminK[bin][t], fkey(smin[t]));
  atomicMax(&st->dmaxK[bin][t], fkey(smax[t]));
}

// ---- finalize: mn, poff, dmin/dmax via monotone clamp, scale ------------
__global__ void k_finalize(const float* __restrict__ u,
                           const float* __restrict__ clampv, Stats* st) {
  int t = threadIdx.x;
  __shared__ float smn[CH];
  float msum = 0.f;
  unsigned kmin = 0xFFFFFFFFu, kmax = 0u;
#pragma unroll
  for (int b = 0; b < NBINS; ++b) {
    msum += st->mnsum[b][t];
    unsigned a = st->dminK[b][t], z = st->dmaxK[b][t];
    kmin = (a < kmin) ? a : kmin;
    kmax = (z > kmax) ? z : kmax;
  }
  float mnv = msum * (1.f / COLS);
  st->mn[t] = mnv;
  smn[t] = mnv;
  __syncthreads();
  float acc = 0.f;
  for (int c = 0; c < CH; ++c) acc += u[c * CH + t] * smn[c];
  st->poff[t] = acc;
  float cv = clampv[t];
  st->clF[t] = cv;
  float dmin = clampf(funkey(kmin) - acc, cv);
  float dmax = clampf(funkey(kmax) - acc, cv);
  float rng = dmax - dmin;
  float sc = 0.f, iv = 0.f;
  if (rng != 0.f) { sc = 255.f / rng; iv = rng / 255.f; }
  st->dminF[t] = dmin; st->scaleF[t] = sc; st->invF[t] = iv;
}

// ---- qsum: per-row sum of dequantized q ---------------------------------
__global__ __launch_bounds__(256) void k_qsum(const unsigned* __restrict__ pq,
                                              long nstride,
                                              Stats* __restrict__ st) {
  __shared__ float w4a[4], w4b[4];
  const int blk = blockIdx.x;
  const int n = blk >> 7, kp = blk & 127;
  const int r0 = 2 * kp, r1 = r0 + 1;
  const float p0 = st->poff[r0], c0 = st->clF[r0], d0 = st->dminF[r0],
              sc0 = st->scaleF[r0], i0 = st->invF[r0];
  const float p1 = st->poff[r1], c1 = st->clF[r1], d1 = st->dminF[r1],
              sc1 = st->scaleF[r1], i1 = st->invF[r1];
  const uint4* p = (const uint4*)(pq + (size_t)n * nstride + (size_t)kp * HWsz);
  float s0 = 0.f, s1 = 0.f;
  for (int i = threadIdx.x; i < HWsz / 4; i += 256) {
    const uint4 w = p[i];
    const unsigned ws[4] = {w.x, w.y, w.z, w.w};
#pragma unroll
    for (int k = 0; k < 4; ++k) {
      s0 += dq(clampf(bf2f((unsigned short)(ws[k] & 0xffffu)) - p0, c0), d0, sc0, i0);
      s1 += dq(clampf(bf2f((unsigned short)(ws[k] >> 16)) - p1, c1), d1, sc1, i1);
    }
  }
  for (int off = 32; off; off >>= 1) {
    s0 += __shfl_down(s0, off);
    s1 += __shfl_down(s1, off);
  }
  int lane = threadIdx.x & 63, wvi = threadIdx.x >> 6;
  if (!lane) { w4a[wvi] = s0; w4b[wvi] = s1; }
  __syncthreads();
  if (threadIdx.x == 0) {
    atomicAdd(&st->qsum[r0], (w4a[0] + w4a[1]) + (w4a[2] + w4a[3]));
    atomicAdd(&st->qsum[r1], (w4b[0] + w4b[1]) + (w4b[2] + w4b[3]));
  }
}

__global__ void k_corr(const float* __restrict__ u, Stats* st) {
  int t = threadIdx.x;
  __shared__ float qm[CH];
  qm[t] = st->qsum[t] * (1.f / COLS);
  __syncthreads();
  float acc = 0.f;
  for (int r = 0; r < CH; ++r) acc += u[t * CH + r] * qm[r];
  st->corr[t] = st->mn[t] - acc;
}

// ---- GEMM2: out = u @ q + corr ------------------------------------------
__global__ __launch_bounds__(256) void k_gemm2(const unsigned* __restrict__ pq,
                                               long nstride,
                                               Stats* __restrict__ st,
                                               float* __restrict__ out) {
  __shared__ __align__(16) unsigned ldsB[2][TN * 20];
  __shared__ float pf[CH], cl[CH], dm[CH], sc[CH], iv[CH], co[CH];

  const int t = threadIdx.x;
  const int lane = t & 63, wv = t >> 6;
  const int g = t & 15, kpl = t >> 4;
  const int c2 = kpl & 3;
  const int q = lane >> 4, r15 = lane & 15;
  const int wsw = (((wv ^ ((g >> 1) & 3)) << 2) | c2);

  const int t0 = blockIdx.x * PBLK;
  const unsigned short* uA = st->u_bf;

  pf[t] = st->poff[t]; cl[t] = st->clF[t]; dm[t] = st->dminF[t];
  sc[t] = st->scaleF[t]; iv[t] = st->invF[t]; co[t] = st->corr[t];
  __syncthreads();

  f32x4 acc[4][4] = {};
  uint4 rW[3];

  auto ld = [&](int gi, int slot) {
    const int tile = t0 + (gi >> 3), kc = gi & 7;
    const int n = tile / 49, hw0 = (tile % 49) * TN;
    rW[slot] = *(const uint4*)(pq + (size_t)n * nstride + (size_t)(kc * 16 + kpl) * HWsz + hw0 + 4 * g);
  };
  auto stage = [&](int gi, int slot) {
    const int kc = gi & 7, buf = gi & 1;
    const int R0 = 2 * (kc * 16 + kpl);
    const float p0 = pf[R0],     q0 = cl[R0],     e0 = dm[R0],     s0 = sc[R0],     v0 = iv[R0];
    const float p1 = pf[R0 + 1], q1 = cl[R0 + 1], e1 = dm[R0 + 1], s1 = sc[R0 + 1], v1 = iv[R0 + 1];
    const unsigned ws[4] = {rW[slot].x, rW[slot].y, rW[slot].z, rW[slot].w};
#pragma unroll
    for (int i = 0; i < 4; ++i) {
      const float a = dq(clampf(bf2f((unsigned short)(ws[i] & 0xffffu)) - p0, q0), e0, s0, v0);
      const float b = dq(clampf(bf2f((unsigned short)(ws[i] >> 16)) - p1, q1), e1, s1, v1);
      ldsB[buf][(4 * g + i) * 20 + wsw] = pack_bf2(a, b);
    }
  };
  auto epi = [&](int tile) {
    const int n = tile / 49, hw0 = (tile % 49) * TN;
#pragma unroll
    for (int mt = 0; mt < 4; ++mt)
#pragma unroll
      for (int reg = 0; reg < 4; ++reg) {
        const int row = 64 * wv + 16 * mt + 4 * q + reg;
        const float cr = co[row];
        const size_t obase = ((size_t)n * CH + row) * HWsz + hw0;
#pragma unroll
        for (int nt = 0; nt < 4; ++nt)
          out[obase + nt * 16 + r15] = acc[mt][nt][reg] + cr;
      }
  };

  ld(0, 0); ld(1, 1); ld(2, 2);
  stage(0, 0);

#pragma unroll
  for (int gi = 0; gi < GI_N; ++gi) {
    wave_barrier();
    const int kc = gi & 7;
    bf16x8 afr[4];
#pragma unroll
    for (int mt = 0; mt < 4; ++mt)
      afr[mt] = *(const bf16x8*)(uA + (64 * wv + 16 * mt + r15) * CH + kc * KB + q * 8);
    bf16x8 bfr[4];
#pragma unroll
    for (int nt = 0; nt < 4; ++nt) {
      const int j = nt * 16 + r15;
      bfr[nt] = *(const bf16x8*)((const unsigned short*)ldsB[gi & 1] +
                                 (size_t)j * 40 + ((q ^ ((j >> 3) & 3)) << 3));
    }
    if (gi + 3 < GI_N) ld(gi + 3, (gi + 3) % 3);
    if (gi + 1 < GI_N) stage(gi + 1, (gi + 1) % 3);
#pragma unroll
    for (int nt = 0; nt < 4; ++nt)
#pragma unroll
      for (int mt = 0; mt < 4; ++mt)
        acc[mt][nt] = __builtin_amdgcn_mfma_f32_16x16x32_bf16(afr[mt], bfr[nt], acc[mt][nt], 0, 0, 0);
    if ((gi & 7) == 7) {
      epi(t0 + (gi >> 3));
#pragma unroll
      for (int mt = 0; mt < 4; ++mt)
#pragma unroll
        for (int nt = 0; nt < 4; ++nt)
          acc[mt][nt] = (f32x4)(0.f);
    }
  }
}

extern "C" void kernel_launch(void* const* d_in, const int* in_sizes, int n_in,
                              void* d_out, int out_size, void* d_ws, size_t ws_size,
                              hipStream_t stream) {
  const float* x  = (const float*)d_in[0];
  const float* u  = (const float*)d_in[1];
  const float* cv = (const float*)d_in[2];
  float* out = (float*)d_out;
  Stats* st = (Stats*)d_ws;

  const size_t pq_off = (sizeof(Stats) + 255) & ~(size_t)255;
  const size_t pq_bytes = (size_t)NIMG * (CH / 2) * HWsz * 4;
  unsigned* pq;
  long nstride;
  if (ws_size >= pq_off + pq_bytes) {
    pq = (unsigned*)((char*)d_ws + pq_off);
    nstride = (long)(CH / 2) * HWsz;
  } else {
    // host pq in the upper half-rows of each image's slab of d_out.
    // Safe: each gemm2 block reads only its own (n, col-range) pq slice and
    // writes only that slice's out rows, after all its reads completed.
    pq = (unsigned*)d_out + (size_t)(CH / 2) * HWsz;
    nstride = (long)CH * HWsz;
  }

  const int gemm_blocks = TILES / PBLK;  // 784

  k_init<<<CH, CH, 0, stream>>>(u, st);
  k_gemm1<<<gemm_blocks, 256, 0, stream>>>(x, st, pq, nstride);
  k_finalize<<<1, CH, 0, stream>>>(u, cv, st);
  k_qsum<<<NIMG * (CH / 2), 256, 0, stream>>>(pq, nstride, st);
  k_corr<<<1, CH, 0, stream>>>(u, st);
  k_gemm2<<<gemm_blocks, 256, 0, stream>>>(pq, nstride, st, out);
}

// Round 2
// 323.179 us; speedup vs baseline: 1.1307x; 1.1307x over previous
//
#include <hip/hip_runtime.h>
#include <hip/hip_bf16.h>
#include <stdint.h>

#define CH    256
#define HWsz  3136
#define NIMG  32
#define COLS  (NIMG * HWsz)   // 100352
#define KB    32
#define TN    64
#define TILES (COLS / TN)     // 1568
#define PBLK  2               // tiles per block
#define NBINS 8               // replicated atomic bins (contention spread)
#define CHUNK (TN * 20)       // unsigned words per K-chunk in LDS

typedef float  f32x4  __attribute__((ext_vector_type(4)));
typedef __bf16 bf16x8 __attribute__((ext_vector_type(8)));

struct Stats {
  float mnsum[NBINS][CH];
  float mn[CH];
  float poff[CH];
  float clF[CH];
  unsigned dminK[NBINS][CH];
  unsigned dmaxK[NBINS][CH];
  float dminF[CH];
  float scaleF[CH];
  float invF[CH];
  float qsum[CH];
  float corr[CH];
  unsigned short u_bf[CH * CH];   // u row-major (A for GEMM2)
  unsigned short uT_bf[CH * CH];  // u transposed (A for GEMM1)
};

__device__ __forceinline__ unsigned short f2bf(float f) {
  union { float f; unsigned u; } v; v.f = f;
  unsigned r = v.u + 0x7fffu + ((v.u >> 16) & 1u);  // RNE
  return (unsigned short)(r >> 16);
}
__device__ __forceinline__ float bf2f(unsigned short b) {
  union { unsigned u; float f; } v; v.u = ((unsigned)b) << 16;
  return v.f;
}
__device__ __forceinline__ unsigned pack_bf2(float a, float b) {
  return (unsigned)f2bf(a) | ((unsigned)f2bf(b) << 16);
}
__device__ __forceinline__ unsigned fkey(float f) {
  unsigned u = __float_as_uint(f);
  return (u & 0x80000000u) ? ~u : (u | 0x80000000u);
}
__device__ __forceinline__ float funkey(unsigned k) {
  unsigned u = (k & 0x80000000u) ? (k & 0x7fffffffu) : ~k;
  return __uint_as_float(u);
}
__device__ __forceinline__ float clampf(float v, float c) {
  return fminf(fmaxf(v, -c), c);
}
__device__ __forceinline__ float dq(float v, float dmin, float sc, float inv) {
  return sc == 0.f ? v : fmaf(rintf((v - dmin) * sc), inv, dmin);
}

// ---- init ---------------------------------------------------------------
__global__ void k_init(const float* __restrict__ u, Stats* st) {
  int b = blockIdx.x, t = threadIdx.x;
  st->u_bf[b * CH + t]  = f2bf(u[b * CH + t]);
  st->uT_bf[b * CH + t] = f2bf(u[t * CH + b]);
  if (b < NBINS) {
    st->mnsum[b][t] = 0.f;
    st->dminK[b][t] = 0xFFFFFFFFu;
    st->dmaxK[b][t] = 0u;
  }
  if (b == 0) st->qsum[t] = 0.f;
}

// ---- GEMM1: p' = uT @ relu(x) raw (bf16 ILV store), fused relu-sums (reg)
// + per-row raw min/max. Whole-K staging: one 16-float4 load burst per tile,
// 2 barriers per tile, 8 barrier-free K-steps of 16 MFMA each.
__global__ __launch_bounds__(256) void k_gemm1(const float* __restrict__ x,
                                               Stats* __restrict__ st,
                                               unsigned* __restrict__ pq,
                                               long nstride) {
  __shared__ __align__(16) unsigned ldsU[8 * CHUNK];   // 40960 B (whole-K panel)
  __shared__ float smin[CH];                           // 1 KB
  __shared__ float smax[CH];                           // 1 KB

  const int t = threadIdx.x;
  const int lane = t & 63, wv = t >> 6;
  const int g = t & 15, cpair = t >> 4;
  const int c2 = cpair & 3;
  const int q = lane >> 4, r15 = lane & 15;
  const int wsw = (((wv ^ ((g >> 1) & 3)) << 2) | c2);  // write swizzle (j>>3 == g>>1)

  const int t0 = blockIdx.x * PBLK;
  const unsigned short* uT = st->uT_bf;

  smin[t] = 1e30f;
  smax[t] = -1e30f;

  f32x4 acc[4][4] = {};
  float4 rA[8], rB[8];
  float relp[8][2] = {};

  auto ldtile = [&](int tile) {
    const int n = tile / 49, hw0 = (tile % 49) * TN;
    const float* p0 = x + (size_t)n * CH * HWsz + (size_t)(2 * cpair) * HWsz + hw0 + 4 * g;
#pragma unroll
    for (int kc = 0; kc < 8; ++kc) {
      const float* p = p0 + (size_t)(kc * KB) * HWsz;
      rA[kc] = *(const float4*)p;
      rB[kc] = *(const float4*)(p + HWsz);
    }
  };
  auto stageall = [&]() {
#pragma unroll
    for (int kc = 0; kc < 8; ++kc) {
      const float a[4] = {fmaxf(rA[kc].x, 0.f), fmaxf(rA[kc].y, 0.f),
                          fmaxf(rA[kc].z, 0.f), fmaxf(rA[kc].w, 0.f)};
      const float b[4] = {fmaxf(rB[kc].x, 0.f), fmaxf(rB[kc].y, 0.f),
                          fmaxf(rB[kc].z, 0.f), fmaxf(rB[kc].w, 0.f)};
      relp[kc][0] += (a[0] + a[1]) + (a[2] + a[3]);
      relp[kc][1] += (b[0] + b[1]) + (b[2] + b[3]);
      unsigned* dst = ldsU + kc * CHUNK;
#pragma unroll
      for (int i = 0; i < 4; ++i)
        dst[(4 * g + i) * 20 + wsw] = pack_bf2(a[i], b[i]);
    }
  };
  auto epi = [&](int tile) {
    const int n = tile / 49, hw0 = (tile % 49) * TN;
#pragma unroll
    for (int mt = 0; mt < 4; ++mt) {
      const int kp0 = 32 * wv + 8 * mt + 2 * q;
      float mn4[4], mx4[4];
#pragma unroll
      for (int nt = 0; nt < 4; ++nt) {
        const unsigned w01 = pack_bf2(acc[mt][nt][0], acc[mt][nt][1]);
        const unsigned w23 = pack_bf2(acc[mt][nt][2], acc[mt][nt][3]);
        const size_t base = (size_t)n * nstride + (size_t)kp0 * HWsz + hw0 + nt * 16 + r15;
        pq[base]        = w01;
        pq[base + HWsz] = w23;
        const float v[4] = {bf2f((unsigned short)(w01 & 0xffffu)), bf2f((unsigned short)(w01 >> 16)),
                            bf2f((unsigned short)(w23 & 0xffffu)), bf2f((unsigned short)(w23 >> 16))};
#pragma unroll
        for (int reg = 0; reg < 4; ++reg) {
          if (nt == 0) { mn4[reg] = v[reg]; mx4[reg] = v[reg]; }
          else { mn4[reg] = fminf(mn4[reg], v[reg]); mx4[reg] = fmaxf(mx4[reg], v[reg]); }
        }
      }
#pragma unroll
      for (int reg = 0; reg < 4; ++reg) {
#pragma unroll
        for (int m = 8; m; m >>= 1) {
          mn4[reg] = fminf(mn4[reg], __shfl_xor(mn4[reg], m));
          mx4[reg] = fmaxf(mx4[reg], __shfl_xor(mx4[reg], m));
        }
        if (r15 == 0) {
          const int row = 64 * wv + 16 * mt + 4 * q + reg;
          smin[row] = fminf(smin[row], mn4[reg]);
          smax[row] = fmaxf(smax[row], mx4[reg]);
        }
      }
    }
  };

  ldtile(t0);

#pragma unroll
  for (int p = 0; p < PBLK; ++p) {
    __syncthreads();      // all waves done reading previous tile's LDS panel
    stageall();
    __syncthreads();      // panel visible
    if (p + 1 < PBLK) ldtile(t0 + p + 1);   // burst-issue next tile's loads
#pragma unroll
    for (int kc = 0; kc < 8; ++kc) {
      bf16x8 afr[4];
#pragma unroll
      for (int mt = 0; mt < 4; ++mt)
        afr[mt] = *(const bf16x8*)(uT + (64 * wv + 16 * mt + r15) * CH + kc * KB + q * 8);
      bf16x8 bfr[4];
#pragma unroll
      for (int nt = 0; nt < 4; ++nt) {
        const int j = nt * 16 + r15;
        bfr[nt] = *(const bf16x8*)((const unsigned short*)(ldsU + kc * CHUNK) +
                                   (size_t)j * 40 + ((q ^ ((j >> 3) & 3)) << 3));
      }
#pragma unroll
      for (int nt = 0; nt < 4; ++nt)
#pragma unroll
        for (int mt = 0; mt < 4; ++mt)
          acc[mt][nt] = __builtin_amdgcn_mfma_f32_16x16x32_bf16(afr[mt], bfr[nt], acc[mt][nt], 0, 0, 0);
    }
    epi(t0 + p);
#pragma unroll
    for (int mt = 0; mt < 4; ++mt)
#pragma unroll
      for (int nt = 0; nt < 4; ++nt)
        acc[mt][nt] = (f32x4)(0.f);
  }

  // relu-sum reduction: regs -> LDS transpose -> one atomic per row per block.
  // scr aliases ldsU (panel no longer needed).
  __syncthreads();
  float (*scr)[17] = (float (*)[17])ldsU;   // 256*17*4 = 17408 B <= 40960 B
#pragma unroll
  for (int kc = 0; kc < 8; ++kc) {
    scr[kc * 32 + 2 * cpair + 0][g] = relp[kc][0];
    scr[kc * 32 + 2 * cpair + 1][g] = relp[kc][1];
  }
  __syncthreads();
  float s = 0.f;
#pragma unroll
  for (int i = 0; i < 16; ++i) s += scr[t][i];
  const int bin = blockIdx.x & (NBINS - 1);
  atomicAdd(&st->mnsum[bin][t], s);
  atomicMin(&st->dminK[bin][t], fkey(smin[t]));
  atomicMax(&st->dmaxK[bin][t], fkey(smax[t]));
}

// ---- finalize: mn, poff, dmin/dmax via monotone clamp, scale ------------
__global__ void k_finalize(const float* __restrict__ u,
                           const float* __restrict__ clampv, Stats* st) {
  int t = threadIdx.x;
  __shared__ float smn[CH];
  float msum = 0.f;
  unsigned kmin = 0xFFFFFFFFu, kmax = 0u;
#pragma unroll
  for (int b = 0; b < NBINS; ++b) {
    msum += st->mnsum[b][t];
    unsigned a = st->dminK[b][t], z = st->dmaxK[b][t];
    kmin = (a < kmin) ? a : kmin;
    kmax = (z > kmax) ? z : kmax;
  }
  float mnv = msum * (1.f / COLS);
  st->mn[t] = mnv;
  smn[t] = mnv;
  __syncthreads();
  float acc = 0.f;
  for (int c = 0; c < CH; ++c) acc += u[c * CH + t] * smn[c];
  st->poff[t] = acc;
  float cv = clampv[t];
  st->clF[t] = cv;
  float dmin = clampf(funkey(kmin) - acc, cv);
  float dmax = clampf(funkey(kmax) - acc, cv);
  float rng = dmax - dmin;
  float sc = 0.f, iv = 0.f;
  if (rng != 0.f) { sc = 255.f / rng; iv = rng / 255.f; }
  st->dminF[t] = dmin; st->scaleF[t] = sc; st->invF[t] = iv;
}

// ---- qsum: per-row sum of dequantized q ---------------------------------
__global__ __launch_bounds__(256) void k_qsum(const unsigned* __restrict__ pq,
                                              long nstride,
                                              Stats* __restrict__ st) {
  __shared__ float w4a[4], w4b[4];
  const int blk = blockIdx.x;
  const int n = blk >> 7, kp = blk & 127;
  const int r0 = 2 * kp, r1 = r0 + 1;
  const float p0 = st->poff[r0], c0 = st->clF[r0], d0 = st->dminF[r0],
              sc0 = st->scaleF[r0], i0 = st->invF[r0];
  const float p1 = st->poff[r1], c1 = st->clF[r1], d1 = st->dminF[r1],
              sc1 = st->scaleF[r1], i1 = st->invF[r1];
  const uint4* p = (const uint4*)(pq + (size_t)n * nstride + (size_t)kp * HWsz);
  float s0 = 0.f, s1 = 0.f;
  for (int i = threadIdx.x; i < HWsz / 4; i += 256) {
    const uint4 w = p[i];
    const unsigned ws[4] = {w.x, w.y, w.z, w.w};
#pragma unroll
    for (int k = 0; k < 4; ++k) {
      s0 += dq(clampf(bf2f((unsigned short)(ws[k] & 0xffffu)) - p0, c0), d0, sc0, i0);
      s1 += dq(clampf(bf2f((unsigned short)(ws[k] >> 16)) - p1, c1), d1, sc1, i1);
    }
  }
  for (int off = 32; off; off >>= 1) {
    s0 += __shfl_down(s0, off);
    s1 += __shfl_down(s1, off);
  }
  int lane = threadIdx.x & 63, wvi = threadIdx.x >> 6;
  if (!lane) { w4a[wvi] = s0; w4b[wvi] = s1; }
  __syncthreads();
  if (threadIdx.x == 0) {
    atomicAdd(&st->qsum[r0], (w4a[0] + w4a[1]) + (w4a[2] + w4a[3]));
    atomicAdd(&st->qsum[r1], (w4b[0] + w4b[1]) + (w4b[2] + w4b[3]));
  }
}

__global__ void k_corr(const float* __restrict__ u, Stats* st) {
  int t = threadIdx.x;
  __shared__ float qm[CH];
  qm[t] = st->qsum[t] * (1.f / COLS);
  __syncthreads();
  float acc = 0.f;
  for (int r = 0; r < CH; ++r) acc += u[t * CH + r] * qm[r];
  st->corr[t] = st->mn[t] - acc;
}

// ---- GEMM2: out = u @ q + corr ------------------------------------------
__global__ __launch_bounds__(256) void k_gemm2(const unsigned* __restrict__ pq,
                                               long nstride,
                                               Stats* __restrict__ st,
                                               float* __restrict__ out) {
  __shared__ __align__(16) unsigned ldsU[8 * CHUNK];   // 40960 B
  __shared__ float pf[CH], cl[CH], dm[CH], sc[CH], iv[CH], co[CH];

  const int t = threadIdx.x;
  const int lane = t & 63, wv = t >> 6;
  const int g = t & 15, kpl = t >> 4;
  const int c2 = kpl & 3;
  const int q = lane >> 4, r15 = lane & 15;
  const int wsw = (((wv ^ ((g >> 1) & 3)) << 2) | c2);

  const int t0 = blockIdx.x * PBLK;
  const unsigned short* uA = st->u_bf;

  pf[t] = st->poff[t]; cl[t] = st->clF[t]; dm[t] = st->dminF[t];
  sc[t] = st->scaleF[t]; iv[t] = st->invF[t]; co[t] = st->corr[t];
  __syncthreads();

  f32x4 acc[4][4] = {};
  uint4 rW[8];

  auto ldtile = [&](int tile) {
    const int n = tile / 49, hw0 = (tile % 49) * TN;
    const unsigned* p0 = pq + (size_t)n * nstride + (size_t)kpl * HWsz + hw0 + 4 * g;
#pragma unroll
    for (int kc = 0; kc < 8; ++kc)
      rW[kc] = *(const uint4*)(p0 + (size_t)(kc * 16) * HWsz);
  };
  auto stageall = [&]() {
#pragma unroll
    for (int kc = 0; kc < 8; ++kc) {
      const int R0 = 2 * (kc * 16 + kpl);
      const float p0 = pf[R0],     q0 = cl[R0],     e0 = dm[R0],     s0 = sc[R0],     v0 = iv[R0];
      const float p1 = pf[R0 + 1], q1 = cl[R0 + 1], e1 = dm[R0 + 1], s1 = sc[R0 + 1], v1 = iv[R0 + 1];
      const unsigned ws[4] = {rW[kc].x, rW[kc].y, rW[kc].z, rW[kc].w};
      unsigned* dst = ldsU + kc * CHUNK;
#pragma unroll
      for (int i = 0; i < 4; ++i) {
        const float a = dq(clampf(bf2f((unsigned short)(ws[i] & 0xffffu)) - p0, q0), e0, s0, v0);
        const float b = dq(clampf(bf2f((unsigned short)(ws[i] >> 16)) - p1, q1), e1, s1, v1);
        dst[(4 * g + i) * 20 + wsw] = pack_bf2(a, b);
      }
    }
  };
  auto epi = [&](int tile) {
    const int n = tile / 49, hw0 = (tile % 49) * TN;
#pragma unroll
    for (int mt = 0; mt < 4; ++mt)
#pragma unroll
      for (int reg = 0; reg < 4; ++reg) {
        const int row = 64 * wv + 16 * mt + 4 * q + reg;
        const float cr = co[row];
        const size_t obase = ((size_t)n * CH + row) * HWsz + hw0;
#pragma unroll
        for (int nt = 0; nt < 4; ++nt)
          out[obase + nt * 16 + r15] = acc[mt][nt][reg] + cr;
      }
  };

  ldtile(t0);

#pragma unroll
  for (int p = 0; p < PBLK; ++p) {
    __syncthreads();
    stageall();
    __syncthreads();
    if (p + 1 < PBLK) ldtile(t0 + p + 1);
#pragma unroll
    for (int kc = 0; kc < 8; ++kc) {
      bf16x8 afr[4];
#pragma unroll
      for (int mt = 0; mt < 4; ++mt)
        afr[mt] = *(const bf16x8*)(uA + (64 * wv + 16 * mt + r15) * CH + kc * KB + q * 8);
      bf16x8 bfr[4];
#pragma unroll
      for (int nt = 0; nt < 4; ++nt) {
        const int j = nt * 16 + r15;
        bfr[nt] = *(const bf16x8*)((const unsigned short*)(ldsU + kc * CHUNK) +
                                   (size_t)j * 40 + ((q ^ ((j >> 3) & 3)) << 3));
      }
#pragma unroll
      for (int nt = 0; nt < 4; ++nt)
#pragma unroll
        for (int mt = 0; mt < 4; ++mt)
          acc[mt][nt] = __builtin_amdgcn_mfma_f32_16x16x32_bf16(afr[mt], bfr[nt], acc[mt][nt], 0, 0, 0);
    }
    epi(t0 + p);
#pragma unroll
    for (int mt = 0; mt < 4; ++mt)
#pragma unroll
      for (int nt = 0; nt < 4; ++nt)
        acc[mt][nt] = (f32x4)(0.f);
  }
}

extern "C" void kernel_launch(void* const* d_in, const int* in_sizes, int n_in,
                              void* d_out, int out_size, void* d_ws, size_t ws_size,
                              hipStream_t stream) {
  const float* x  = (const float*)d_in[0];
  const float* u  = (const float*)d_in[1];
  const float* cv = (const float*)d_in[2];
  float* out = (float*)d_out;
  Stats* st = (Stats*)d_ws;

  const size_t pq_off = (sizeof(Stats) + 255) & ~(size_t)255;
  const size_t pq_bytes = (size_t)NIMG * (CH / 2) * HWsz * 4;
  unsigned* pq;
  long nstride;
  if (ws_size >= pq_off + pq_bytes) {
    pq = (unsigned*)((char*)d_ws + pq_off);
    nstride = (long)(CH / 2) * HWsz;
  } else {
    // host pq in the upper half-rows of each image's slab of d_out.
    // Safe: each gemm2 block reads only its own (n, col-range) pq slice and
    // writes only that slice's out rows, after all its reads completed.
    pq = (unsigned*)d_out + (size_t)(CH / 2) * HWsz;
    nstride = (long)CH * HWsz;
  }

  const int gemm_blocks = TILES / PBLK;  // 784

  k_init<<<CH, CH, 0, stream>>>(u, st);
  k_gemm1<<<gemm_blocks, 256, 0, stream>>>(x, st, pq, nstride);
  k_finalize<<<1, CH, 0, stream>>>(u, cv, st);
  k_qsum<<<NIMG * (CH / 2), 256, 0, stream>>>(pq, nstride, st);
  k_corr<<<1, CH, 0, stream>>>(u, st);
  k_gemm2<<<gemm_blocks, 256, 0, stream>>>(pq, nstride, st, out);
}

// Round 3
// 322.738 us; speedup vs baseline: 1.1323x; 1.0014x over previous
//
#include <hip/hip_runtime.h>
#include <hip/hip_bf16.h>
#include <stdint.h>

#define CH    256
#define HWsz  3136
#define NIMG  32
#define COLS  (NIMG * HWsz)   // 100352
#define KB    32
#define TN    64
#define TILES (COLS / TN)     // 1568
#define NBINS 8               // replicated atomic bins (contention spread)
#define CHUNK (TN * 20)       // unsigned words per K-chunk in LDS

typedef float  f32x4  __attribute__((ext_vector_type(4)));
typedef __bf16 bf16x8 __attribute__((ext_vector_type(8)));

struct Stats {
  float mnsum[NBINS][CH];
  float mn[CH];
  float poff[CH];
  float clF[CH];
  unsigned dminK[NBINS][CH];
  unsigned dmaxK[NBINS][CH];
  float dminF[CH];
  float scaleF[CH];
  float invF[CH];
  float qsum[CH];
  float corr[CH];
  unsigned short u_bf[CH * CH];   // u row-major (A for GEMM2)
  unsigned short uT_bf[CH * CH];  // u transposed (A for GEMM1)
};

__device__ __forceinline__ unsigned short f2bf(float f) {
  union { float f; unsigned u; } v; v.f = f;
  unsigned r = v.u + 0x7fffu + ((v.u >> 16) & 1u);  // RNE
  return (unsigned short)(r >> 16);
}
__device__ __forceinline__ float bf2f(unsigned short b) {
  union { unsigned u; float f; } v; v.u = ((unsigned)b) << 16;
  return v.f;
}
__device__ __forceinline__ unsigned pack_bf2(float a, float b) {
  return (unsigned)f2bf(a) | ((unsigned)f2bf(b) << 16);
}
__device__ __forceinline__ unsigned fkey(float f) {
  unsigned u = __float_as_uint(f);
  return (u & 0x80000000u) ? ~u : (u | 0x80000000u);
}
__device__ __forceinline__ float funkey(unsigned k) {
  unsigned u = (k & 0x80000000u) ? (k & 0x7fffffffu) : ~k;
  return __uint_as_float(u);
}
__device__ __forceinline__ float clampf(float v, float c) {
  return fminf(fmaxf(v, -c), c);
}
__device__ __forceinline__ float dq(float v, float dmin, float sc, float inv) {
  return sc == 0.f ? v : fmaf(rintf((v - dmin) * sc), inv, dmin);
}

// ---- init ---------------------------------------------------------------
__global__ void k_init(const float* __restrict__ u, Stats* st) {
  int b = blockIdx.x, t = threadIdx.x;
  st->u_bf[b * CH + t]  = f2bf(u[b * CH + t]);
  st->uT_bf[b * CH + t] = f2bf(u[t * CH + b]);
  if (b < NBINS) {
    st->mnsum[b][t] = 0.f;
    st->dminK[b][t] = 0xFFFFFFFFu;
    st->dmaxK[b][t] = 0u;
  }
  if (b == 0) st->qsum[t] = 0.f;
}

// ---- GEMM1: p' = uT @ relu(x) raw (bf16 ILV store), fused relu-sums (reg)
// + per-row raw min/max. 1 tile/block (grid 1568), whole-K LDS panel,
// one barrier, VGPR<=128 (launch_bounds 4 waves/EU), 40KB LDS -> 4 blocks/CU.
__global__ __launch_bounds__(256, 4) void k_gemm1(const float* __restrict__ x,
                                                  Stats* __restrict__ st,
                                                  unsigned* __restrict__ pq,
                                                  long nstride) {
  __shared__ __align__(16) unsigned ldsU[8 * CHUNK];   // 40960 B exactly

  const int t = threadIdx.x;
  const int lane = t & 63, wv = t >> 6;
  const int g = t & 15, cpair = t >> 4;
  const int c2 = cpair & 3;
  const int q = lane >> 4, r15 = lane & 15;
  const int wsw = (((wv ^ ((g >> 1) & 3)) << 2) | c2);  // write swizzle (j>>3 == g>>1)

  const int tile = blockIdx.x;
  const int n = tile / 49, hw0 = (tile % 49) * TN;
  const unsigned short* uT = st->uT_bf;
  const int bin = blockIdx.x & (NBINS - 1);

  float4 rA[4], rB[4];
  float relp[8][2] = {};

  const float* pbase = x + (size_t)n * CH * HWsz + (size_t)(2 * cpair) * HWsz + hw0 + 4 * g;

  auto ld4 = [&](int h) {
#pragma unroll
    for (int i = 0; i < 4; ++i) {
      const float* p = pbase + (size_t)((4 * h + i) * KB) * HWsz;
      rA[i] = *(const float4*)p;
      rB[i] = *(const float4*)(p + HWsz);
    }
  };
  auto stage4 = [&](int h) {
#pragma unroll
    for (int i = 0; i < 4; ++i) {
      const int kc = 4 * h + i;
      const float a[4] = {fmaxf(rA[i].x, 0.f), fmaxf(rA[i].y, 0.f),
                          fmaxf(rA[i].z, 0.f), fmaxf(rA[i].w, 0.f)};
      const float b[4] = {fmaxf(rB[i].x, 0.f), fmaxf(rB[i].y, 0.f),
                          fmaxf(rB[i].z, 0.f), fmaxf(rB[i].w, 0.f)};
      relp[kc][0] += (a[0] + a[1]) + (a[2] + a[3]);
      relp[kc][1] += (b[0] + b[1]) + (b[2] + b[3]);
      unsigned* dst = ldsU + kc * CHUNK;
#pragma unroll
      for (int j = 0; j < 4; ++j)
        dst[(4 * g + j) * 20 + wsw] = pack_bf2(a[j], b[j]);
    }
  };

  ld4(0);
  stage4(0);
  ld4(1);
  stage4(1);
  __syncthreads();   // panel visible to all waves

  f32x4 acc[4][4];
#pragma unroll
  for (int mt = 0; mt < 4; ++mt)
#pragma unroll
    for (int nt = 0; nt < 4; ++nt)
      acc[mt][nt] = (f32x4)(0.f);

#pragma unroll
  for (int kc = 0; kc < 8; ++kc) {
    bf16x8 afr[4];
#pragma unroll
    for (int mt = 0; mt < 4; ++mt)
      afr[mt] = *(const bf16x8*)(uT + (64 * wv + 16 * mt + r15) * CH + kc * KB + q * 8);
    bf16x8 bfr[4];
#pragma unroll
    for (int nt = 0; nt < 4; ++nt) {
      const int j = nt * 16 + r15;
      bfr[nt] = *(const bf16x8*)((const unsigned short*)(ldsU + kc * CHUNK) +
                                 (size_t)j * 40 + ((q ^ ((j >> 3) & 3)) << 3));
    }
#pragma unroll
    for (int nt = 0; nt < 4; ++nt)
#pragma unroll
      for (int mt = 0; mt < 4; ++mt)
        acc[mt][nt] = __builtin_amdgcn_mfma_f32_16x16x32_bf16(afr[mt], bfr[nt], acc[mt][nt], 0, 0, 0);
  }

  // epilogue: pack/store pq + per-row min/max -> direct atomics (rows are
  // wave-exclusive: row = 64wv+16mt+4q+reg covers 0..255 exactly once)
#pragma unroll
  for (int mt = 0; mt < 4; ++mt) {
    const int kp0 = 32 * wv + 8 * mt + 2 * q;
    float mn4[4], mx4[4];
#pragma unroll
    for (int nt = 0; nt < 4; ++nt) {
      const unsigned w01 = pack_bf2(acc[mt][nt][0], acc[mt][nt][1]);
      const unsigned w23 = pack_bf2(acc[mt][nt][2], acc[mt][nt][3]);
      const size_t base = (size_t)n * nstride + (size_t)kp0 * HWsz + hw0 + nt * 16 + r15;
      pq[base]        = w01;
      pq[base + HWsz] = w23;
      const float v[4] = {bf2f((unsigned short)(w01 & 0xffffu)), bf2f((unsigned short)(w01 >> 16)),
                          bf2f((unsigned short)(w23 & 0xffffu)), bf2f((unsigned short)(w23 >> 16))};
#pragma unroll
      for (int reg = 0; reg < 4; ++reg) {
        if (nt == 0) { mn4[reg] = v[reg]; mx4[reg] = v[reg]; }
        else { mn4[reg] = fminf(mn4[reg], v[reg]); mx4[reg] = fmaxf(mx4[reg], v[reg]); }
      }
    }
#pragma unroll
    for (int reg = 0; reg < 4; ++reg) {
#pragma unroll
      for (int m = 8; m; m >>= 1) {
        mn4[reg] = fminf(mn4[reg], __shfl_xor(mn4[reg], m));
        mx4[reg] = fmaxf(mx4[reg], __shfl_xor(mx4[reg], m));
      }
      if (r15 == 0) {
        const int row = 64 * wv + 16 * mt + 4 * q + reg;
        atomicMin(&st->dminK[bin][row], fkey(mn4[reg]));
        atomicMax(&st->dmaxK[bin][row], fkey(mx4[reg]));
      }
    }
  }

  // relu-sum reduction: regs -> LDS transpose -> one atomic per row per block.
  // scr aliases ldsU (panel no longer needed).
  __syncthreads();
  float (*scr)[17] = (float (*)[17])ldsU;   // 256*17*4 = 17408 B <= 40960 B
#pragma unroll
  for (int kc = 0; kc < 8; ++kc) {
    scr[kc * 32 + 2 * cpair + 0][g] = relp[kc][0];
    scr[kc * 32 + 2 * cpair + 1][g] = relp[kc][1];
  }
  __syncthreads();
  float s = 0.f;
#pragma unroll
  for (int i = 0; i < 16; ++i) s += scr[t][i];
  atomicAdd(&st->mnsum[bin][t], s);
}

// ---- finalize: mn, poff, dmin/dmax via monotone clamp, scale ------------
__global__ void k_finalize(const float* __restrict__ u,
                           const float* __restrict__ clampv, Stats* st) {
  int t = threadIdx.x;
  __shared__ float smn[CH];
  float msum = 0.f;
  unsigned kmin = 0xFFFFFFFFu, kmax = 0u;
#pragma unroll
  for (int b = 0; b < NBINS; ++b) {
    msum += st->mnsum[b][t];
    unsigned a = st->dminK[b][t], z = st->dmaxK[b][t];
    kmin = (a < kmin) ? a : kmin;
    kmax = (z > kmax) ? z : kmax;
  }
  float mnv = msum * (1.f / COLS);
  st->mn[t] = mnv;
  smn[t] = mnv;
  __syncthreads();
  float acc = 0.f;
  for (int c = 0; c < CH; ++c) acc += u[c * CH + t] * smn[c];
  st->poff[t] = acc;
  float cv = clampv[t];
  st->clF[t] = cv;
  float dmin = clampf(funkey(kmin) - acc, cv);
  float dmax = clampf(funkey(kmax) - acc, cv);
  float rng = dmax - dmin;
  float sc = 0.f, iv = 0.f;
  if (rng != 0.f) { sc = 255.f / rng; iv = rng / 255.f; }
  st->dminF[t] = dmin; st->scaleF[t] = sc; st->invF[t] = iv;
}

// ---- qsum: per-row sum of dequantized q ---------------------------------
__global__ __launch_bounds__(256) void k_qsum(const unsigned* __restrict__ pq,
                                              long nstride,
                                              Stats* __restrict__ st) {
  __shared__ float w4a[4], w4b[4];
  const int blk = blockIdx.x;
  const int n = blk >> 7, kp = blk & 127;
  const int r0 = 2 * kp, r1 = r0 + 1;
  const float p0 = st->poff[r0], c0 = st->clF[r0], d0 = st->dminF[r0],
              sc0 = st->scaleF[r0], i0 = st->invF[r0];
  const float p1 = st->poff[r1], c1 = st->clF[r1], d1 = st->dminF[r1],
              sc1 = st->scaleF[r1], i1 = st->invF[r1];
  const uint4* p = (const uint4*)(pq + (size_t)n * nstride + (size_t)kp * HWsz);
  float s0 = 0.f, s1 = 0.f;
  for (int i = threadIdx.x; i < HWsz / 4; i += 256) {
    const uint4 w = p[i];
    const unsigned ws[4] = {w.x, w.y, w.z, w.w};
#pragma unroll
    for (int k = 0; k < 4; ++k) {
      s0 += dq(clampf(bf2f((unsigned short)(ws[k] & 0xffffu)) - p0, c0), d0, sc0, i0);
      s1 += dq(clampf(bf2f((unsigned short)(ws[k] >> 16)) - p1, c1), d1, sc1, i1);
    }
  }
  for (int off = 32; off; off >>= 1) {
    s0 += __shfl_down(s0, off);
    s1 += __shfl_down(s1, off);
  }
  int lane = threadIdx.x & 63, wvi = threadIdx.x >> 6;
  if (!lane) { w4a[wvi] = s0; w4b[wvi] = s1; }
  __syncthreads();
  if (threadIdx.x == 0) {
    atomicAdd(&st->qsum[r0], (w4a[0] + w4a[1]) + (w4a[2] + w4a[3]));
    atomicAdd(&st->qsum[r1], (w4b[0] + w4b[1]) + (w4b[2] + w4b[3]));
  }
}

__global__ void k_corr(const float* __restrict__ u, Stats* st) {
  int t = threadIdx.x;
  __shared__ float qm[CH];
  qm[t] = st->qsum[t] * (1.f / COLS);
  __syncthreads();
  float acc = 0.f;
  for (int r = 0; r < CH; ++r) acc += u[t * CH + r] * qm[r];
  st->corr[t] = st->mn[t] - acc;
}

// ---- GEMM2: out = u @ q + corr ------------------------------------------
__global__ __launch_bounds__(256, 4) void k_gemm2(const unsigned* __restrict__ pq,
                                                  long nstride,
                                                  Stats* __restrict__ st,
                                                  float* __restrict__ out) {
  __shared__ __align__(16) unsigned ldsU[8 * CHUNK];   // 40960 B
  __shared__ float pf[CH], cl[CH], dm[CH], sc[CH], iv[CH];  // 5120 B

  const int t = threadIdx.x;
  const int lane = t & 63, wv = t >> 6;
  const int g = t & 15, kpl = t >> 4;
  const int c2 = kpl & 3;
  const int q = lane >> 4, r15 = lane & 15;
  const int wsw = (((wv ^ ((g >> 1) & 3)) << 2) | c2);

  const int tile = blockIdx.x;
  const int n = tile / 49, hw0 = (tile % 49) * TN;
  const unsigned short* uA = st->u_bf;

  pf[t] = st->poff[t]; cl[t] = st->clF[t]; dm[t] = st->dminF[t];
  sc[t] = st->scaleF[t]; iv[t] = st->invF[t];
  __syncthreads();

  uint4 rW[8];
  const unsigned* p0g = pq + (size_t)n * nstride + (size_t)kpl * HWsz + hw0 + 4 * g;
#pragma unroll
  for (int kc = 0; kc < 8; ++kc)
    rW[kc] = *(const uint4*)(p0g + (size_t)(kc * 16) * HWsz);

#pragma unroll
  for (int kc = 0; kc < 8; ++kc) {
    const int R0 = 2 * (kc * 16 + kpl);
    const float pp0 = pf[R0],     q0 = cl[R0],     e0 = dm[R0],     s0 = sc[R0],     v0 = iv[R0];
    const float pp1 = pf[R0 + 1], q1 = cl[R0 + 1], e1 = dm[R0 + 1], s1 = sc[R0 + 1], v1 = iv[R0 + 1];
    const unsigned ws[4] = {rW[kc].x, rW[kc].y, rW[kc].z, rW[kc].w};
    unsigned* dst = ldsU + kc * CHUNK;
#pragma unroll
    for (int i = 0; i < 4; ++i) {
      const float a = dq(clampf(bf2f((unsigned short)(ws[i] & 0xffffu)) - pp0, q0), e0, s0, v0);
      const float b = dq(clampf(bf2f((unsigned short)(ws[i] >> 16)) - pp1, q1), e1, s1, v1);
      dst[(4 * g + i) * 20 + wsw] = pack_bf2(a, b);
    }
  }
  __syncthreads();

  f32x4 acc[4][4];
#pragma unroll
  for (int mt = 0; mt < 4; ++mt)
#pragma unroll
    for (int nt = 0; nt < 4; ++nt)
      acc[mt][nt] = (f32x4)(0.f);

#pragma unroll
  for (int kc = 0; kc < 8; ++kc) {
    bf16x8 afr[4];
#pragma unroll
    for (int mt = 0; mt < 4; ++mt)
      afr[mt] = *(const bf16x8*)(uA + (64 * wv + 16 * mt + r15) * CH + kc * KB + q * 8);
    bf16x8 bfr[4];
#pragma unroll
    for (int nt = 0; nt < 4; ++nt) {
      const int j = nt * 16 + r15;
      bfr[nt] = *(const bf16x8*)((const unsigned short*)(ldsU + kc * CHUNK) +
                                 (size_t)j * 40 + ((q ^ ((j >> 3) & 3)) << 3));
    }
#pragma unroll
    for (int nt = 0; nt < 4; ++nt)
#pragma unroll
      for (int mt = 0; mt < 4; ++mt)
        acc[mt][nt] = __builtin_amdgcn_mfma_f32_16x16x32_bf16(afr[mt], bfr[nt], acc[mt][nt], 0, 0, 0);
  }

  // epilogue: corr read from global (L2-hot), saves 1KB LDS
#pragma unroll
  for (int mt = 0; mt < 4; ++mt)
#pragma unroll
    for (int reg = 0; reg < 4; ++reg) {
      const int row = 64 * wv + 16 * mt + 4 * q + reg;
      const float cr = st->corr[row];
      const size_t obase = ((size_t)n * CH + row) * HWsz + hw0;
#pragma unroll
      for (int nt = 0; nt < 4; ++nt)
        out[obase + nt * 16 + r15] = acc[mt][nt][reg] + cr;
    }
}

extern "C" void kernel_launch(void* const* d_in, const int* in_sizes, int n_in,
                              void* d_out, int out_size, void* d_ws, size_t ws_size,
                              hipStream_t stream) {
  const float* x  = (const float*)d_in[0];
  const float* u  = (const float*)d_in[1];
  const float* cv = (const float*)d_in[2];
  float* out = (float*)d_out;
  Stats* st = (Stats*)d_ws;

  const size_t pq_off = (sizeof(Stats) + 255) & ~(size_t)255;
  const size_t pq_bytes = (size_t)NIMG * (CH / 2) * HWsz * 4;
  unsigned* pq;
  long nstride;
  if (ws_size >= pq_off + pq_bytes) {
    pq = (unsigned*)((char*)d_ws + pq_off);
    nstride = (long)(CH / 2) * HWsz;
  } else {
    // host pq in the upper half-rows of each image's slab of d_out.
    // Safe: each gemm2 block reads only its own (n, col-range) pq slice and
    // writes only that slice's out rows, after all its reads completed.
    pq = (unsigned*)d_out + (size_t)(CH / 2) * HWsz;
    nstride = (long)CH * HWsz;
  }

  k_init<<<CH, CH, 0, stream>>>(u, st);
  k_gemm1<<<TILES, 256, 0, stream>>>(x, st, pq, nstride);
  k_finalize<<<1, CH, 0, stream>>>(u, cv, st);
  k_qsum<<<NIMG * (CH / 2), 256, 0, stream>>>(pq, nstride, st);
  k_corr<<<1, CH, 0, stream>>>(u, st);
  k_gemm2<<<TILES, 256, 0, stream>>>(pq, nstride, st, out);
}

// Round 5
// 285.942 us; speedup vs baseline: 1.2780x; 1.1287x over previous
//
#include <hip/hip_runtime.h>
#include <hip/hip_bf16.h>
#include <stdint.h>

#define CH    256
#define HWsz  3136
#define NIMG  32
#define COLS  (NIMG * HWsz)   // 100352
#define KB    32
#define TN    64
#define TILES (COLS / TN)     // 1568
#define NBINS 8               // replicated atomic bins (contention spread)
#define CHUNK (TN * 20)       // unsigned words per K-chunk in LDS

typedef float  f32x4  __attribute__((ext_vector_type(4)));
typedef __bf16 bf16x8 __attribute__((ext_vector_type(8)));

struct Stats {
  float mnsum[NBINS][CH];
  float mn[CH];
  float poff[CH];
  float clF[CH];
  unsigned dminK[NBINS][CH];
  unsigned dmaxK[NBINS][CH];
  float dminF[CH];
  float scaleF[CH];
  float invF[CH];
  float qsum[CH];
  float corr[CH];
  unsigned short u_bf[CH * CH];   // u row-major (A for GEMM2)
  unsigned short uT_bf[CH * CH];  // u transposed (A for GEMM1)
};

__device__ __forceinline__ unsigned short f2bf(float f) {
  union { float f; unsigned u; } v; v.f = f;
  unsigned r = v.u + 0x7fffu + ((v.u >> 16) & 1u);  // RNE
  return (unsigned short)(r >> 16);
}
__device__ __forceinline__ float bf2f(unsigned short b) {
  union { unsigned u; float f; } v; v.u = ((unsigned)b) << 16;
  return v.f;
}
__device__ __forceinline__ unsigned pack_bf2(float a, float b) {
  return (unsigned)f2bf(a) | ((unsigned)f2bf(b) << 16);
}
__device__ __forceinline__ unsigned fkey(float f) {
  unsigned u = __float_as_uint(f);
  return (u & 0x80000000u) ? ~u : (u | 0x80000000u);
}
__device__ __forceinline__ float funkey(unsigned k) {
  unsigned u = (k & 0x80000000u) ? (k & 0x7fffffffu) : ~k;
  return __uint_as_float(u);
}
__device__ __forceinline__ float clampf(float v, float c) {
  return fminf(fmaxf(v, -c), c);
}
__device__ __forceinline__ float dq(float v, float dmin, float sc, float inv) {
  return sc == 0.f ? v : fmaf(rintf((v - dmin) * sc), inv, dmin);
}

// ---- init ---------------------------------------------------------------
__global__ void k_init(const float* __restrict__ u, Stats* st) {
  int b = blockIdx.x, t = threadIdx.x;
  st->u_bf[b * CH + t]  = f2bf(u[b * CH + t]);
  st->uT_bf[b * CH + t] = f2bf(u[t * CH + b]);
  if (b < NBINS) {
    st->mnsum[b][t] = 0.f;
    st->dminK[b][t] = 0xFFFFFFFFu;
    st->dmaxK[b][t] = 0u;
  }
  if (b == 0) st->qsum[t] = 0.f;
}

// ---- GEMM1: p' = uT @ relu(x) raw (bf16 ILV store), fused relu-sums (reg)
// + per-row raw min/max. 512 threads/block (8 waves), per-wave 32x64 output,
// acc[2][4]=32 regs. NO occupancy attributes: round-3 (launch_bounds(256,4))
// squeezed to 64 VGPR + 150MB scratch; round-4 (waves_per_eu(4,4)) failed
// correctness post-timing. Natural allocation; pressure ~90 regs.
__global__ __launch_bounds__(512)
void k_gemm1(const float* __restrict__ x,
             Stats* __restrict__ st,
             unsigned* __restrict__ pq,
             long nstride) {
  __shared__ __align__(16) unsigned ldsU[8 * CHUNK];   // 40960 B

  const int t = threadIdx.x;
  const int lane = t & 63, wv = t >> 6;        // wv 0..7
  const int g = t & 15, cp = (t >> 4) & 15, half = t >> 8;
  const int q = lane >> 4, r15 = lane & 15;
  const int wsw = (((cp >> 2) ^ ((g >> 1) & 3)) << 2) | (cp & 3);  // write swizzle

  const int tile = blockIdx.x;
  const int n = tile / 49, hw0 = (tile % 49) * TN;
  const unsigned short* uT = st->uT_bf;
  const int bin = blockIdx.x & (NBINS - 1);

  float4 rA[4], rB[4];
  float relp[4][2] = {};

  // each thread stages 4 K-chunks (its half): channels 2cp,2cp+1 of chunks 4*half..4*half+3
  const float* pbase = x + (size_t)n * CH * HWsz + (size_t)(2 * cp) * HWsz + hw0 + 4 * g;
#pragma unroll
  for (int i = 0; i < 4; ++i) {
    const float* p = pbase + (size_t)((4 * half + i) * KB) * HWsz;
    rA[i] = *(const float4*)p;
    rB[i] = *(const float4*)(p + HWsz);
  }
#pragma unroll
  for (int i = 0; i < 4; ++i) {
    const int kc = 4 * half + i;
    const float a[4] = {fmaxf(rA[i].x, 0.f), fmaxf(rA[i].y, 0.f),
                        fmaxf(rA[i].z, 0.f), fmaxf(rA[i].w, 0.f)};
    const float b[4] = {fmaxf(rB[i].x, 0.f), fmaxf(rB[i].y, 0.f),
                        fmaxf(rB[i].z, 0.f), fmaxf(rB[i].w, 0.f)};
    relp[i][0] += (a[0] + a[1]) + (a[2] + a[3]);
    relp[i][1] += (b[0] + b[1]) + (b[2] + b[3]);
    unsigned* dst = ldsU + kc * CHUNK;
#pragma unroll
    for (int j = 0; j < 4; ++j)
      dst[(4 * g + j) * 20 + wsw] = pack_bf2(a[j], b[j]);
  }
  __syncthreads();   // panel visible to all waves

  f32x4 acc[2][4];
#pragma unroll
  for (int mt = 0; mt < 2; ++mt)
#pragma unroll
    for (int nt = 0; nt < 4; ++nt)
      acc[mt][nt] = (f32x4)(0.f);

#pragma unroll
  for (int kc = 0; kc < 8; ++kc) {
    bf16x8 afr[2];
#pragma unroll
    for (int mt = 0; mt < 2; ++mt)
      afr[mt] = *(const bf16x8*)(uT + (32 * wv + 16 * mt + r15) * CH + kc * KB + q * 8);
    bf16x8 bfr[4];
#pragma unroll
    for (int nt = 0; nt < 4; ++nt) {
      const int j = nt * 16 + r15;
      bfr[nt] = *(const bf16x8*)((const unsigned short*)(ldsU + kc * CHUNK) +
                                 (size_t)j * 40 + ((q ^ ((j >> 3) & 3)) << 3));
    }
#pragma unroll
    for (int nt = 0; nt < 4; ++nt)
#pragma unroll
      for (int mt = 0; mt < 2; ++mt)
        acc[mt][nt] = __builtin_amdgcn_mfma_f32_16x16x32_bf16(afr[mt], bfr[nt], acc[mt][nt], 0, 0, 0);
  }

  // epilogue: pack/store pq + per-row min/max -> direct atomics (rows are
  // wave-exclusive: row = 32wv+16mt+4q+reg covers 0..255 exactly once)
#pragma unroll
  for (int mt = 0; mt < 2; ++mt) {
    const int kp0 = 16 * wv + 8 * mt + 2 * q;
    float mn4[4], mx4[4];
#pragma unroll
    for (int nt = 0; nt < 4; ++nt) {
      const unsigned w01 = pack_bf2(acc[mt][nt][0], acc[mt][nt][1]);
      const unsigned w23 = pack_bf2(acc[mt][nt][2], acc[mt][nt][3]);
      const size_t base = (size_t)n * nstride + (size_t)kp0 * HWsz + hw0 + nt * 16 + r15;
      pq[base]        = w01;
      pq[base + HWsz] = w23;
      const float v[4] = {bf2f((unsigned short)(w01 & 0xffffu)), bf2f((unsigned short)(w01 >> 16)),
                          bf2f((unsigned short)(w23 & 0xffffu)), bf2f((unsigned short)(w23 >> 16))};
#pragma unroll
      for (int reg = 0; reg < 4; ++reg) {
        if (nt == 0) { mn4[reg] = v[reg]; mx4[reg] = v[reg]; }
        else { mn4[reg] = fminf(mn4[reg], v[reg]); mx4[reg] = fmaxf(mx4[reg], v[reg]); }
      }
    }
#pragma unroll
    for (int reg = 0; reg < 4; ++reg) {
#pragma unroll
      for (int m = 8; m; m >>= 1) {
        mn4[reg] = fminf(mn4[reg], __shfl_xor(mn4[reg], m));
        mx4[reg] = fmaxf(mx4[reg], __shfl_xor(mx4[reg], m));
      }
      if (r15 == 0) {
        const int row = 32 * wv + 16 * mt + 4 * q + reg;
        atomicMin(&st->dminK[bin][row], fkey(mn4[reg]));
        atomicMax(&st->dmaxK[bin][row], fkey(mx4[reg]));
      }
    }
  }

  // relu-sum reduction: regs -> LDS transpose -> one atomic per row per block.
  // scr aliases ldsU (panel no longer needed).
  __syncthreads();
  float (*scr)[17] = (float (*)[17])ldsU;   // 256*17*4 = 17408 B <= 40960 B
#pragma unroll
  for (int i = 0; i < 4; ++i) {
    const int kc = 4 * half + i;
    scr[kc * KB + 2 * cp + 0][g] = relp[i][0];
    scr[kc * KB + 2 * cp + 1][g] = relp[i][1];
  }
  __syncthreads();
  if (t < CH) {
    float s = 0.f;
#pragma unroll
    for (int i = 0; i < 16; ++i) s += scr[t][i];
    atomicAdd(&st->mnsum[bin][t], s);
  }
}

// ---- finalize: mn, poff, dmin/dmax via monotone clamp, scale ------------
__global__ void k_finalize(const float* __restrict__ u,
                           const float* __restrict__ clampv, Stats* st) {
  int t = threadIdx.x;
  __shared__ float smn[CH];
  float msum = 0.f;
  unsigned kmin = 0xFFFFFFFFu, kmax = 0u;
#pragma unroll
  for (int b = 0; b < NBINS; ++b) {
    msum += st->mnsum[b][t];
    unsigned a = st->dminK[b][t], z = st->dmaxK[b][t];
    kmin = (a < kmin) ? a : kmin;
    kmax = (z > kmax) ? z : kmax;
  }
  float mnv = msum * (1.f / COLS);
  st->mn[t] = mnv;
  smn[t] = mnv;
  __syncthreads();
  float acc = 0.f;
  for (int c = 0; c < CH; ++c) acc += u[c * CH + t] * smn[c];
  st->poff[t] = acc;
  float cv = clampv[t];
  st->clF[t] = cv;
  float dmin = clampf(funkey(kmin) - acc, cv);
  float dmax = clampf(funkey(kmax) - acc, cv);
  float rng = dmax - dmin;
  float sc = 0.f, iv = 0.f;
  if (rng != 0.f) { sc = 255.f / rng; iv = rng / 255.f; }
  st->dminF[t] = dmin; st->scaleF[t] = sc; st->invF[t] = iv;
}

// ---- qsum: per-row sum of dequantized q ---------------------------------
__global__ __launch_bounds__(256) void k_qsum(const unsigned* __restrict__ pq,
                                              long nstride,
                                              Stats* __restrict__ st) {
  __shared__ float w4a[4], w4b[4];
  const int blk = blockIdx.x;
  const int n = blk >> 7, kp = blk & 127;
  const int r0 = 2 * kp, r1 = r0 + 1;
  const float p0 = st->poff[r0], c0 = st->clF[r0], d0 = st->dminF[r0],
              sc0 = st->scaleF[r0], i0 = st->invF[r0];
  const float p1 = st->poff[r1], c1 = st->clF[r1], d1 = st->dminF[r1],
              sc1 = st->scaleF[r1], i1 = st->invF[r1];
  const uint4* p = (const uint4*)(pq + (size_t)n * nstride + (size_t)kp * HWsz);
  float s0 = 0.f, s1 = 0.f;
  for (int i = threadIdx.x; i < HWsz / 4; i += 256) {
    const uint4 w = p[i];
    const unsigned ws[4] = {w.x, w.y, w.z, w.w};
#pragma unroll
    for (int k = 0; k < 4; ++k) {
      s0 += dq(clampf(bf2f((unsigned short)(ws[k] & 0xffffu)) - p0, c0), d0, sc0, i0);
      s1 += dq(clampf(bf2f((unsigned short)(ws[k] >> 16)) - p1, c1), d1, sc1, i1);
    }
  }
  for (int off = 32; off; off >>= 1) {
    s0 += __shfl_down(s0, off);
    s1 += __shfl_down(s1, off);
  }
  int lane = threadIdx.x & 63, wvi = threadIdx.x >> 6;
  if (!lane) { w4a[wvi] = s0; w4b[wvi] = s1; }
  __syncthreads();
  if (threadIdx.x == 0) {
    atomicAdd(&st->qsum[r0], (w4a[0] + w4a[1]) + (w4a[2] + w4a[3]));
    atomicAdd(&st->qsum[r1], (w4b[0] + w4b[1]) + (w4b[2] + w4b[3]));
  }
}

__global__ void k_corr(const float* __restrict__ u, Stats* st) {
  int t = threadIdx.x;
  __shared__ float qm[CH];
  qm[t] = st->qsum[t] * (1.f / COLS);
  __syncthreads();
  float acc = 0.f;
  for (int r = 0; r < CH; ++r) acc += u[t * CH + r] * qm[r];
  st->corr[t] = st->mn[t] - acc;
}

// ---- GEMM2: out = u @ q + corr ------------------------------------------
__global__ __launch_bounds__(512)
void k_gemm2(const unsigned* __restrict__ pq,
             long nstride,
             Stats* __restrict__ st,
             float* __restrict__ out) {
  __shared__ __align__(16) unsigned ldsU[8 * CHUNK];        // 40960 B
  __shared__ float pf[CH], cl[CH], dm[CH], sc[CH], iv[CH];  // 5120 B

  const int t = threadIdx.x;
  const int lane = t & 63, wv = t >> 6;        // wv 0..7
  const int g = t & 15, kpl = (t >> 4) & 15, half = t >> 8;
  const int q = lane >> 4, r15 = lane & 15;
  const int wsw = (((kpl >> 2) ^ ((g >> 1) & 3)) << 2) | (kpl & 3);

  const int tile = blockIdx.x;
  const int n = tile / 49, hw0 = (tile % 49) * TN;
  const unsigned short* uA = st->u_bf;

  if (t < CH) {
    pf[t] = st->poff[t]; cl[t] = st->clF[t]; dm[t] = st->dminF[t];
    sc[t] = st->scaleF[t]; iv[t] = st->invF[t];
  }
  __syncthreads();

  uint4 rW[4];
  const unsigned* p0g = pq + (size_t)n * nstride + (size_t)kpl * HWsz + hw0 + 4 * g;
#pragma unroll
  for (int i = 0; i < 4; ++i)
    rW[i] = *(const uint4*)(p0g + (size_t)((4 * half + i) * 16) * HWsz);

#pragma unroll
  for (int i = 0; i < 4; ++i) {
    const int kc = 4 * half + i;
    const int R0 = 2 * (kc * 16 + kpl);
    const float pp0 = pf[R0],     q0 = cl[R0],     e0 = dm[R0],     s0 = sc[R0],     v0 = iv[R0];
    const float pp1 = pf[R0 + 1], q1 = cl[R0 + 1], e1 = dm[R0 + 1], s1 = sc[R0 + 1], v1 = iv[R0 + 1];
    const unsigned ws[4] = {rW[i].x, rW[i].y, rW[i].z, rW[i].w};
    unsigned* dst = ldsU + kc * CHUNK;
#pragma unroll
    for (int j = 0; j < 4; ++j) {
      const float a = dq(clampf(bf2f((unsigned short)(ws[j] & 0xffffu)) - pp0, q0), e0, s0, v0);
      const float b = dq(clampf(bf2f((unsigned short)(ws[j] >> 16)) - pp1, q1), e1, s1, v1);
      dst[(4 * g + j) * 20 + wsw] = pack_bf2(a, b);
    }
  }
  __syncthreads();

  f32x4 acc[2][4];
#pragma unroll
  for (int mt = 0; mt < 2; ++mt)
#pragma unroll
    for (int nt = 0; nt < 4; ++nt)
      acc[mt][nt] = (f32x4)(0.f);

#pragma unroll
  for (int kc = 0; kc < 8; ++kc) {
    bf16x8 afr[2];
#pragma unroll
    for (int mt = 0; mt < 2; ++mt)
      afr[mt] = *(const bf16x8*)(uA + (32 * wv + 16 * mt + r15) * CH + kc * KB + q * 8);
    bf16x8 bfr[4];
#pragma unroll
    for (int nt = 0; nt < 4; ++nt) {
      const int j = nt * 16 + r15;
      bfr[nt] = *(const bf16x8*)((const unsigned short*)(ldsU + kc * CHUNK) +
                                 (size_t)j * 40 + ((q ^ ((j >> 3) & 3)) << 3));
    }
#pragma unroll
    for (int nt = 0; nt < 4; ++nt)
#pragma unroll
      for (int mt = 0; mt < 2; ++mt)
        acc[mt][nt] = __builtin_amdgcn_mfma_f32_16x16x32_bf16(afr[mt], bfr[nt], acc[mt][nt], 0, 0, 0);
  }

  // epilogue: corr read from global (L2-hot)
#pragma unroll
  for (int mt = 0; mt < 2; ++mt)
#pragma unroll
    for (int reg = 0; reg < 4; ++reg) {
      const int row = 32 * wv + 16 * mt + 4 * q + reg;
      const float cr = st->corr[row];
      const size_t obase = ((size_t)n * CH + row) * HWsz + hw0;
#pragma unroll
      for (int nt = 0; nt < 4; ++nt)
        out[obase + nt * 16 + r15] = acc[mt][nt][reg] + cr;
    }
}

extern "C" void kernel_launch(void* const* d_in, const int* in_sizes, int n_in,
                              void* d_out, int out_size, void* d_ws, size_t ws_size,
                              hipStream_t stream) {
  const float* x  = (const float*)d_in[0];
  const float* u  = (const float*)d_in[1];
  const float* cv = (const float*)d_in[2];
  float* out = (float*)d_out;
  Stats* st = (Stats*)d_ws;

  const size_t pq_off = (sizeof(Stats) + 255) & ~(size_t)255;
  const size_t pq_bytes = (size_t)NIMG * (CH / 2) * HWsz * 4;
  unsigned* pq;
  long nstride;
  if (ws_size >= pq_off + pq_bytes) {
    pq = (unsigned*)((char*)d_ws + pq_off);
    nstride = (long)(CH / 2) * HWsz;
  } else {
    // host pq in the upper half-rows of each image's slab of d_out.
    // Safe: each gemm2 block reads only its own (n, col-range) pq slice and
    // writes only that slice's out rows, after all its reads completed.
    pq = (unsigned*)d_out + (size_t)(CH / 2) * HWsz;
    nstride = (long)CH * HWsz;
  }

  k_init<<<CH, CH, 0, stream>>>(u, st);
  k_gemm1<<<TILES, 512, 0, stream>>>(x, st, pq, nstride);
  k_finalize<<<1, CH, 0, stream>>>(u, cv, st);
  k_qsum<<<NIMG * (CH / 2), 256, 0, stream>>>(pq, nstride, st);
  k_corr<<<1, CH, 0, stream>>>(u, st);
  k_gemm2<<<TILES, 512, 0, stream>>>(pq, nstride, st, out);
}